// Round 1
// baseline (115.206 us; speedup 1.0000x reference)
//
#include <hip/hip_runtime.h>

#define BN_EPS 1e-5f

__global__ __launch_bounds__(256) void naf_policy_kernel(
    const float* __restrict__ inputs, const float* __restrict__ u,
    const float* __restrict__ w1c, const float* __restrict__ b1c,
    const float* __restrict__ w1o, const float* __restrict__ b1o,
    const float* __restrict__ w2c, const float* __restrict__ b2c,
    const float* __restrict__ w2o, const float* __restrict__ b2o,
    const float* __restrict__ w3c, const float* __restrict__ b3c,
    const float* __restrict__ w3o, const float* __restrict__ b3o,
    const float* __restrict__ g0, const float* __restrict__ be0,
    const float* __restrict__ W1, const float* __restrict__ bl1,
    const float* __restrict__ W2, const float* __restrict__ bl2,
    const float* __restrict__ Vw, const float* __restrict__ Vb,
    const float* __restrict__ Mw, const float* __restrict__ Mb,
    const float* __restrict__ Lw, const float* __restrict__ Lb,
    float* __restrict__ out)
{
    __shared__ float pooled[3][48];   // per-branch pooled features, n = o*3 + p
    __shared__ float xcat[2][32];     // concat(c1,c2,c3, inputs[:,24:])
    __shared__ float xn[2][32];       // after batchnorm
    __shared__ float h1[2][128];
    __shared__ float h2[2][128];
    __shared__ float Lm[2][8][8];     // masked L (strict lower + exp diag)
    __shared__ float mu_s[2][8];
    __shared__ float V_s[2];

    const int tid = threadIdx.x;

    // ---- Phase 1: conv1d(2->16,k4,p1) + ReLU + maxpool2 (drops t=6) ----
    // work item: (branch br, o, p) -> pooled[br][o*3+p] = max_{dt} relu(conv(o, 2p+dt))
    if (tid < 144) {
        const int br = tid / 48;
        const int n  = tid % 48;
        const int o  = n / 3;
        const int p  = n % 3;
        const float* wc = (br == 0) ? w1c : (br == 1 ? w2c : w3c);
        const float* bc = (br == 0) ? b1c : (br == 1 ? b2c : b3c);
        // channel c of the conv input is batch-row c of inputs, cols br*8..br*8+7
        const float* seg = inputs + br * 8;  // seg[c*32 + pos]
        float best = 0.0f;  // relu floor
        #pragma unroll
        for (int dt = 0; dt < 2; ++dt) {
            const int t = 2 * p + dt;
            float acc = bc[o];
            #pragma unroll
            for (int c = 0; c < 2; ++c) {
                #pragma unroll
                for (int k = 0; k < 4; ++k) {
                    const int pos = t + k - 1;  // padding 1
                    const float xv = (pos >= 0 && pos < 8) ? seg[c * 32 + pos] : 0.0f;
                    acc = fmaf(xv, wc[o * 8 + c * 4 + k], acc);
                }
            }
            acc = fmaxf(acc, 0.0f);
            best = fmaxf(best, acc);
        }
        pooled[br][n] = best;
    } else if (tid < 160) {
        // copy inputs[:, 24:] into xcat tail
        const int q = tid - 144;
        const int r = q >> 3, col = q & 7;
        xcat[r][24 + col] = inputs[r * 32 + 24 + col];
    }
    __syncthreads();

    // ---- Phase 2: branch Linear(48->16), reshape(2,8) into xcat ----
    if (tid < 48) {
        const int br = tid / 16;
        const int j  = tid % 16;
        const float* wo = (br == 0) ? w1o : (br == 1 ? w2o : w3o);
        const float* bo = (br == 0) ? b1o : (br == 1 ? b2o : b3o);
        float acc = bo[j];
        #pragma unroll 8
        for (int n = 0; n < 48; ++n)
            acc = fmaf(pooled[br][n], wo[j * 48 + n], acc);
        const int r = j >> 3, col = j & 7;
        xcat[r][br * 8 + col] = acc;
    }
    __syncthreads();

    // ---- Phase 3: BatchNorm1d train mode (biased var over batch of 2) ----
    if (tid < 32) {
        const float a = xcat[0][tid], b = xcat[1][tid];
        const float m = 0.5f * (a + b);
        const float da = a - m, db = b - m;
        const float v = 0.5f * (da * da + db * db);
        const float inv = rsqrtf(v + BN_EPS);
        const float g = g0[tid], be = be0[tid];
        xn[0][tid] = fmaf(g * da, inv, be);
        xn[1][tid] = fmaf(g * db, inv, be);
    }
    __syncthreads();

    // ---- Phase 4: h1 = tanh(xn @ W1^T + bl1), 256 outputs ----
    {
        const int r = tid >> 7, j = tid & 127;
        float acc = bl1[j];
        const float* w = W1 + j * 32;
        #pragma unroll 8
        for (int k = 0; k < 32; ++k) acc = fmaf(xn[r][k], w[k], acc);
        h1[r][j] = tanhf(acc);
    }
    __syncthreads();

    // ---- Phase 5: h2 = tanh(h1 @ W2^T + bl2) ----
    {
        const int r = tid >> 7, j = tid & 127;
        float acc = bl2[j];
        const float* w = W2 + j * 128;
        #pragma unroll 8
        for (int k = 0; k < 128; ++k) acc = fmaf(h1[r][k], w[k], acc);
        h2[r][j] = tanhf(acc);
    }
    __syncthreads();

    // ---- Phase 6: heads (L: 128 items, mu: 16, V: 2) ----
    if (tid < 128) {
        const int r = tid >> 6, idx = tid & 63;
        float acc = Lb[idx];
        const float* w = Lw + idx * 128;
        #pragma unroll 8
        for (int k = 0; k < 128; ++k) acc = fmaf(h2[r][k], w[k], acc);
        const int i = idx >> 3, jj = idx & 7;
        float val;
        if (jj < i)       val = acc;          // strict lower
        else if (jj == i) val = expf(acc);    // exp diagonal
        else              val = 0.0f;
        Lm[r][i][jj] = val;
    } else if (tid < 144) {
        const int q = tid - 128;
        const int r = q >> 3, j = q & 7;
        float acc = Mb[j];
        const float* w = Mw + j * 128;
        #pragma unroll 8
        for (int k = 0; k < 128; ++k) acc = fmaf(h2[r][k], w[k], acc);
        const float m = tanhf(acc);
        mu_s[r][j] = m;
        out[r * 8 + j] = m;                   // mu -> out[0..15]
    } else if (tid < 146) {
        const int r = tid - 144;
        float acc = Vb[0];
        #pragma unroll 8
        for (int k = 0; k < 128; ++k) acc = fmaf(h2[r][k], Vw[k], acc);
        V_s[r] = acc;
        out[18 + r] = acc;                    // V -> out[18..19]
    }
    __syncthreads();

    // ---- Phase 7: Q = -0.5 * d^T (L L^T) d + V = -0.5 * sum_k (d . L[:,k])^2 + V ----
    if (tid < 2) {
        const int r = tid;
        float d[8];
        #pragma unroll
        for (int j = 0; j < 8; ++j) d[j] = u[r * 8 + j] - mu_s[r][j];
        float s = 0.0f;
        #pragma unroll
        for (int k = 0; k < 8; ++k) {
            float c = 0.0f;
            #pragma unroll
            for (int i = 0; i < 8; ++i) c = fmaf(d[i], Lm[r][i][k], c);
            s = fmaf(c, c, s);
        }
        out[16 + r] = fmaf(-0.5f, s, V_s[r]);  // Q -> out[16..17]
    }
}

extern "C" void kernel_launch(void* const* d_in, const int* in_sizes, int n_in,
                              void* d_out, int out_size, void* d_ws, size_t ws_size,
                              hipStream_t stream) {
    (void)in_sizes; (void)n_in; (void)d_ws; (void)ws_size; (void)out_size;
    const float* inputs = (const float*)d_in[0];
    const float* u      = (const float*)d_in[1];
    const float* w1c    = (const float*)d_in[2];
    const float* b1c    = (const float*)d_in[3];
    const float* w1o    = (const float*)d_in[4];
    const float* b1o    = (const float*)d_in[5];
    const float* w2c    = (const float*)d_in[6];
    const float* b2c    = (const float*)d_in[7];
    const float* w2o    = (const float*)d_in[8];
    const float* b2o    = (const float*)d_in[9];
    const float* w3c    = (const float*)d_in[10];
    const float* b3c    = (const float*)d_in[11];
    const float* w3o    = (const float*)d_in[12];
    const float* b3o    = (const float*)d_in[13];
    const float* g0     = (const float*)d_in[14];
    const float* be0    = (const float*)d_in[15];
    const float* W1     = (const float*)d_in[16];
    const float* bl1    = (const float*)d_in[17];
    const float* W2     = (const float*)d_in[18];
    const float* bl2    = (const float*)d_in[19];
    const float* Vw     = (const float*)d_in[20];
    const float* Vb     = (const float*)d_in[21];
    const float* Mw     = (const float*)d_in[22];
    const float* Mb     = (const float*)d_in[23];
    const float* Lw     = (const float*)d_in[24];
    const float* Lb     = (const float*)d_in[25];

    naf_policy_kernel<<<1, 256, 0, stream>>>(
        inputs, u, w1c, b1c, w1o, b1o, w2c, b2c, w2o, b2o, w3c, b3c, w3o, b3o,
        g0, be0, W1, bl1, W2, bl2, Vw, Vb, Mw, Mb, Lw, Lb, (float*)d_out);
}

// Round 2
// 114.092 us; speedup vs baseline: 1.0098x; 1.0098x over previous
//
#include <hip/hip_runtime.h>

#define BN_EPS 1e-5f

__global__ __launch_bounds__(512) void naf_policy_kernel(
    const float* __restrict__ inputs, const float* __restrict__ u,
    const float* __restrict__ w1c, const float* __restrict__ b1c,
    const float* __restrict__ w1o, const float* __restrict__ b1o,
    const float* __restrict__ w2c, const float* __restrict__ b2c,
    const float* __restrict__ w2o, const float* __restrict__ b2o,
    const float* __restrict__ w3c, const float* __restrict__ b3c,
    const float* __restrict__ w3o, const float* __restrict__ b3o,
    const float* __restrict__ g0, const float* __restrict__ be0,
    const float* __restrict__ W1, const float* __restrict__ bl1,
    const float* __restrict__ W2, const float* __restrict__ bl2,
    const float* __restrict__ Vw, const float* __restrict__ Vb,
    const float* __restrict__ Mw, const float* __restrict__ Mb,
    const float* __restrict__ Lw, const float* __restrict__ Lb,
    float* __restrict__ out)
{
    // ---- staged weights (loaded by waves 1-7 at t=0, overlapped w/ phases 1-3) ----
    __shared__ alignas(16) float sW1[128 * 32];    // 16 KB
    __shared__ alignas(16) float sW2[128 * 128];   // 64 KB
    __shared__ alignas(16) float sLw[64 * 128];    // 32 KB
    __shared__ alignas(16) float sMw[8 * 128];     //  4 KB
    __shared__ alignas(16) float sVw[128];
    __shared__ alignas(16) float sbl1[128];
    __shared__ alignas(16) float sbl2[128];
    __shared__ alignas(16) float sLb[64];
    __shared__ alignas(16) float sMb[8];
    __shared__ alignas(16) float su[16];
    __shared__ float sVb;
    // ---- activations ----
    __shared__ float pooled[3][48];
    __shared__ float xcat[2][32];
    __shared__ alignas(16) float xn[2][32];
    __shared__ alignas(16) float h1[2][128];
    __shared__ alignas(16) float h2[2][128];
    __shared__ float Lm[2][8][8];
    __shared__ float mu_s[2][8];
    __shared__ float V_s[2];

    const int tid = threadIdx.x;

    if (tid >= 64) {
        // ---- Staging: 448 threads stream all big operands into LDS ----
        const int t = tid - 64;  // 0..447
        {
            const float4* s = (const float4*)W2; float4* d = (float4*)sW2;
            #pragma unroll
            for (int j = 0; j < 10; ++j) { int i = t + j * 448; if (i < 4096) d[i] = s[i]; }
        }
        {
            const float4* s = (const float4*)Lw; float4* d = (float4*)sLw;
            #pragma unroll
            for (int j = 0; j < 5; ++j) { int i = t + j * 448; if (i < 2048) d[i] = s[i]; }
        }
        {
            const float4* s = (const float4*)W1; float4* d = (float4*)sW1;
            #pragma unroll
            for (int j = 0; j < 3; ++j) { int i = t + j * 448; if (i < 1024) d[i] = s[i]; }
        }
        if (t < 256)                 ((float4*)sMw)[t]        = ((const float4*)Mw)[t];
        else if (t < 288)            ((float4*)sVw)[t - 256]  = ((const float4*)Vw)[t - 256];
        else if (t < 320)            ((float4*)sbl1)[t - 288] = ((const float4*)bl1)[t - 288];
        else if (t < 352)            ((float4*)sbl2)[t - 320] = ((const float4*)bl2)[t - 320];
        else if (t < 368)            ((float4*)sLb)[t - 352]  = ((const float4*)Lb)[t - 352];
        else if (t < 370)            ((float4*)sMb)[t - 368]  = ((const float4*)Mb)[t - 368];
        else if (t < 374)            ((float4*)su)[t - 370]   = ((const float4*)u)[t - 370];
        else if (t == 374)           sVb = Vb[0];
    } else {
        // ---- Phase 1 (wave 0): conv1d(2->16,k4,p1)+ReLU+maxpool2 + tail copy ----
        for (int it = tid; it < 160; it += 64) {
            if (it < 144) {
                const int br = it / 48;
                const int n  = it % 48;
                const int o  = n / 3;
                const int p  = n % 3;
                const float* wc = (br == 0) ? w1c : (br == 1 ? w2c : w3c);
                const float* bc = (br == 0) ? b1c : (br == 1 ? b2c : b3c);
                const float* seg = inputs + br * 8;  // seg[c*32 + pos]
                float best = 0.0f;  // relu floor
                #pragma unroll
                for (int dt = 0; dt < 2; ++dt) {
                    const int tpos = 2 * p + dt;
                    float acc = bc[o];
                    #pragma unroll
                    for (int c = 0; c < 2; ++c) {
                        #pragma unroll
                        for (int k = 0; k < 4; ++k) {
                            const int pos = tpos + k - 1;  // padding 1
                            const float xv = (pos >= 0 && pos < 8) ? seg[c * 32 + pos] : 0.0f;
                            acc = fmaf(xv, wc[o * 8 + c * 4 + k], acc);
                        }
                    }
                    best = fmaxf(best, fmaxf(acc, 0.0f));
                }
                pooled[br][n] = best;
            } else {
                const int q = it - 144;
                const int r = q >> 3, col = q & 7;
                xcat[r][24 + col] = inputs[r * 32 + 24 + col];
            }
        }
    }
    __syncthreads();

    // ---- Phase 2: branch Linear(48->16) ----
    if (tid < 48) {
        const int br = tid / 16;
        const int j  = tid % 16;
        const float* wo = (br == 0) ? w1o : (br == 1 ? w2o : w3o);
        const float* bo = (br == 0) ? b1o : (br == 1 ? b2o : b3o);
        float acc = bo[j];
        #pragma unroll 8
        for (int n = 0; n < 48; ++n)
            acc = fmaf(pooled[br][n], wo[j * 48 + n], acc);
        const int r = j >> 3, col = j & 7;
        xcat[r][br * 8 + col] = acc;
    }
    __syncthreads();

    // ---- Phase 3: BatchNorm1d train mode (biased var over batch of 2) ----
    if (tid < 32) {
        const float a = xcat[0][tid], b = xcat[1][tid];
        const float m = 0.5f * (a + b);
        const float da = a - m, db = b - m;
        const float v = 0.5f * (da * da + db * db);
        const float inv = rsqrtf(v + BN_EPS);
        const float g = g0[tid], be = be0[tid];
        xn[0][tid] = fmaf(g * da, inv, be);
        xn[1][tid] = fmaf(g * db, inv, be);
    }
    __syncthreads();

    // ---- Phase 4: h1 = tanh(xn @ W1^T + bl1), dual-row per thread ----
    if (tid < 128) {
        const float4* w  = (const float4*)(sW1 + tid * 32);
        const float4* x0 = (const float4*)(&xn[0][0]);
        const float4* x1 = (const float4*)(&xn[1][0]);
        float s00 = 0.f, s01 = 0.f, s02 = 0.f, s03 = 0.f;
        float s10 = 0.f, s11 = 0.f, s12 = 0.f, s13 = 0.f;
        #pragma unroll
        for (int k = 0; k < 8; ++k) {
            const float4 wv = w[k], a = x0[k], b = x1[k];
            s00 = fmaf(a.x, wv.x, s00); s01 = fmaf(a.y, wv.y, s01);
            s02 = fmaf(a.z, wv.z, s02); s03 = fmaf(a.w, wv.w, s03);
            s10 = fmaf(b.x, wv.x, s10); s11 = fmaf(b.y, wv.y, s11);
            s12 = fmaf(b.z, wv.z, s12); s13 = fmaf(b.w, wv.w, s13);
        }
        const float bsum = sbl1[tid];
        h1[0][tid] = tanhf(((s00 + s01) + (s02 + s03)) + bsum);
        h1[1][tid] = tanhf(((s10 + s11) + (s12 + s13)) + bsum);
    }
    __syncthreads();

    // ---- Phase 5: h2 = tanh(h1 @ W2^T + bl2), dual-row ----
    if (tid < 128) {
        const float4* w  = (const float4*)(sW2 + tid * 128);
        const float4* x0 = (const float4*)(&h1[0][0]);
        const float4* x1 = (const float4*)(&h1[1][0]);
        float s00 = 0.f, s01 = 0.f, s02 = 0.f, s03 = 0.f;
        float s10 = 0.f, s11 = 0.f, s12 = 0.f, s13 = 0.f;
        #pragma unroll 8
        for (int k = 0; k < 32; ++k) {
            const float4 wv = w[k], a = x0[k], b = x1[k];
            s00 = fmaf(a.x, wv.x, s00); s01 = fmaf(a.y, wv.y, s01);
            s02 = fmaf(a.z, wv.z, s02); s03 = fmaf(a.w, wv.w, s03);
            s10 = fmaf(b.x, wv.x, s10); s11 = fmaf(b.y, wv.y, s11);
            s12 = fmaf(b.z, wv.z, s12); s13 = fmaf(b.w, wv.w, s13);
        }
        const float bsum = sbl2[tid];
        h2[0][tid] = tanhf(((s00 + s01) + (s02 + s03)) + bsum);
        h2[1][tid] = tanhf(((s10 + s11) + (s12 + s13)) + bsum);
    }
    __syncthreads();

    // ---- Phase 6: heads. L: 64 threads (dual-row); mu: 8; V: 2 ----
    if (tid < 64) {
        const float4* w  = (const float4*)(sLw + tid * 128);
        const float4* x0 = (const float4*)(&h2[0][0]);
        const float4* x1 = (const float4*)(&h2[1][0]);
        float s00 = 0.f, s01 = 0.f, s02 = 0.f, s03 = 0.f;
        float s10 = 0.f, s11 = 0.f, s12 = 0.f, s13 = 0.f;
        #pragma unroll 8
        for (int k = 0; k < 32; ++k) {
            const float4 wv = w[k], a = x0[k], b = x1[k];
            s00 = fmaf(a.x, wv.x, s00); s01 = fmaf(a.y, wv.y, s01);
            s02 = fmaf(a.z, wv.z, s02); s03 = fmaf(a.w, wv.w, s03);
            s10 = fmaf(b.x, wv.x, s10); s11 = fmaf(b.y, wv.y, s11);
            s12 = fmaf(b.z, wv.z, s12); s13 = fmaf(b.w, wv.w, s13);
        }
        const float a0 = ((s00 + s01) + (s02 + s03)) + sLb[tid];
        const float a1 = ((s10 + s11) + (s12 + s13)) + sLb[tid];
        const int i = tid >> 3, jj = tid & 7;
        float v0, v1;
        if (jj < i)       { v0 = a0;       v1 = a1; }
        else if (jj == i) { v0 = expf(a0); v1 = expf(a1); }
        else              { v0 = 0.f;      v1 = 0.f; }
        Lm[0][i][jj] = v0;
        Lm[1][i][jj] = v1;
    } else if (tid < 72) {
        const int j = tid - 64;
        const float4* w  = (const float4*)(sMw + j * 128);
        const float4* x0 = (const float4*)(&h2[0][0]);
        const float4* x1 = (const float4*)(&h2[1][0]);
        float s0 = 0.f, s1 = 0.f;
        #pragma unroll 8
        for (int k = 0; k < 32; ++k) {
            const float4 wv = w[k], a = x0[k], b = x1[k];
            s0 = fmaf(a.x, wv.x, s0); s0 = fmaf(a.y, wv.y, s0);
            s0 = fmaf(a.z, wv.z, s0); s0 = fmaf(a.w, wv.w, s0);
            s1 = fmaf(b.x, wv.x, s1); s1 = fmaf(b.y, wv.y, s1);
            s1 = fmaf(b.z, wv.z, s1); s1 = fmaf(b.w, wv.w, s1);
        }
        const float m0 = tanhf(s0 + sMb[j]);
        const float m1 = tanhf(s1 + sMb[j]);
        mu_s[0][j] = m0; mu_s[1][j] = m1;
        out[j] = m0; out[8 + j] = m1;         // mu -> out[0..15]
    } else if (tid < 74) {
        const int r = tid - 72;
        const float4* w = (const float4*)sVw;
        const float4* x = (const float4*)(&h2[r][0]);
        float s = 0.f;
        #pragma unroll 8
        for (int k = 0; k < 32; ++k) {
            const float4 wv = w[k], a = x[k];
            s = fmaf(a.x, wv.x, s); s = fmaf(a.y, wv.y, s);
            s = fmaf(a.z, wv.z, s); s = fmaf(a.w, wv.w, s);
        }
        s += sVb;
        V_s[r] = s;
        out[18 + r] = s;                      // V -> out[18..19]
    }
    __syncthreads();

    // ---- Phase 7: Q = -0.5 * sum_k (d . L[:,k])^2 + V ----
    if (tid < 2) {
        const int r = tid;
        float d[8];
        #pragma unroll
        for (int j = 0; j < 8; ++j) d[j] = su[r * 8 + j] - mu_s[r][j];
        float s = 0.0f;
        #pragma unroll
        for (int k = 0; k < 8; ++k) {
            float c = 0.0f;
            #pragma unroll
            for (int i = 0; i < 8; ++i) c = fmaf(d[i], Lm[r][i][k], c);
            s = fmaf(c, c, s);
        }
        out[16 + r] = fmaf(-0.5f, s, V_s[r]);  // Q -> out[16..17]
    }
}

extern "C" void kernel_launch(void* const* d_in, const int* in_sizes, int n_in,
                              void* d_out, int out_size, void* d_ws, size_t ws_size,
                              hipStream_t stream) {
    (void)in_sizes; (void)n_in; (void)d_ws; (void)ws_size; (void)out_size;
    const float* inputs = (const float*)d_in[0];
    const float* u      = (const float*)d_in[1];
    const float* w1c    = (const float*)d_in[2];
    const float* b1c    = (const float*)d_in[3];
    const float* w1o    = (const float*)d_in[4];
    const float* b1o    = (const float*)d_in[5];
    const float* w2c    = (const float*)d_in[6];
    const float* b2c    = (const float*)d_in[7];
    const float* w2o    = (const float*)d_in[8];
    const float* b2o    = (const float*)d_in[9];
    const float* w3c    = (const float*)d_in[10];
    const float* b3c    = (const float*)d_in[11];
    const float* w3o    = (const float*)d_in[12];
    const float* b3o    = (const float*)d_in[13];
    const float* g0     = (const float*)d_in[14];
    const float* be0    = (const float*)d_in[15];
    const float* W1     = (const float*)d_in[16];
    const float* bl1    = (const float*)d_in[17];
    const float* W2     = (const float*)d_in[18];
    const float* bl2    = (const float*)d_in[19];
    const float* Vw     = (const float*)d_in[20];
    const float* Vb     = (const float*)d_in[21];
    const float* Mw     = (const float*)d_in[22];
    const float* Mb     = (const float*)d_in[23];
    const float* Lw     = (const float*)d_in[24];
    const float* Lb     = (const float*)d_in[25];

    naf_policy_kernel<<<1, 512, 0, stream>>>(
        inputs, u, w1c, b1c, w1o, b1o, w2c, b2c, w2o, b2o, w3c, b3c, w3o, b3o,
        g0, be0, W1, bl1, W2, bl2, Vw, Vb, Mw, Mb, Lw, Lb, (float*)d_out);
}